// Round 1
// baseline (270.060 us; speedup 1.0000x reference)
//
#include <hip/hip_runtime.h>
#include <cstdint>

#define T_  2048
#define D_  64
#define BH_ 32
#define W_  256
// LDS row stride: 132 floats = 528 B, 16B-aligned so float4 LDS reads are legal;
// breaks the 64-lane same-bank pattern on transposed staging writes (8-way, negligible).
#define LDP 132

// Kernel 1: per (b,h,i): sliding-window sum over pop rows -> denom per d,
// wave-allreduce of 1/denom across the 64 lanes (lane == d), then store
// gfs[i][d] = gf[i][d] / rowsum_i   with rowsum_i = cnt*(64/suminv - 0.5) (analytic).
__global__ __launch_bounds__(256) void k1_genefit(const float* __restrict__ pop,
                                                  float* __restrict__ gfs) {
  const int bh = blockIdx.y;
  const int i0 = blockIdx.x * 128;
  const int w  = threadIdx.x >> 6;   // wave id: 4 waves, 32 rows each
  const int d  = threadIdx.x & 63;   // lane == feature dim
  const int ib = i0 + w * 32;

  const float* P = pop + (size_t)bh * T_ * D_ + d;
  float*       G = gfs + (size_t)bh * T_ * D_ + d;

  // init window sum for first row ib: window = [max(0, ib-255), ib]
  float isum = 0.f;
  int s0 = ib - (W_ - 1); if (s0 < 0) s0 = 0;
  for (int j = s0; j <= ib; ++j) isum += P[(size_t)j * D_];

  for (int r = 0; r < 32; ++r) {
    const int i = ib + r;
    if (r > 0) {
      isum += P[(size_t)i * D_];
      const int jd = i - W_;
      if (jd >= 0) isum -= P[(size_t)jd * D_];
    }
    const float cnt   = (i + 1 < W_) ? (float)(i + 1) : (float)W_;
    const float denom = isum / cnt + 0.5f;
    const float rinv  = 1.0f / denom;
    // wave64 butterfly allreduce of rinv -> suminv
    float s = rinv;
    #pragma unroll
    for (int m = 32; m >= 1; m >>= 1) s += __shfl_xor(s, m);
    float rowsum = cnt * (64.0f / s - 0.5f);
    rowsum = fmaxf(rowsum, 1e-10f);
    const float s2 = 1.0f / (rowsum * s);   // gfs = rinv/(suminv*rowsum)
    G[(size_t)i * D_] = rinv * s2;
  }
}

// Kernel 2: banded GEMM. Block = (b,h) x 128-row i-tile. 3 diagonal 128x128
// j-sub-tiles; 16x16 threads, 8x8 fp32 register tile each; A/B staged
// transposed in LDS ([d][row], stride LDP). Also zero-fills the row segments
// outside the 384-wide band so every output element is written every call.
__global__ __launch_bounds__(256) void k2_orgfit(const float* __restrict__ pop,
                                                 const float* __restrict__ gfs,
                                                 float* __restrict__ out) {
  __shared__ float At[64 * LDP];
  __shared__ float Bt[64 * LDP];
  const int bh  = blockIdx.y;
  const int i0  = blockIdx.x * 128;
  const int tid = threadIdx.x;
  const int tx  = tid & 15;
  const int ty  = tid >> 4;

  const float* Pb = pop + (size_t)bh * T_ * D_;
  const float* Gb = gfs + (size_t)bh * T_ * D_;
  float*       Ob = out + (size_t)bh * T_ * T_;

  // stage A (gfs rows i0..i0+127), transposed
  for (int e = tid; e < 64 * 128; e += 256) {
    const int d = e & 63, r = e >> 6;
    At[d * LDP + r] = Gb[(size_t)(i0 + r) * D_ + d];
  }

  // zero-fill columns [0, max(i0-256,0)) and [i0+128, 2048) for all 128 rows
  {
    int L = i0 - 256; if (L < 0) L = 0;
    const int R  = i0 + 128;
    const int L4 = L >> 2;
    const int W4 = L4 + ((T_ - R) >> 2);
    const float4 z4 = make_float4(0.f, 0.f, 0.f, 0.f);
    for (int idx = tid; idx < 128 * W4; idx += 256) {
      const int r   = idx / W4;
      const int c4  = idx - r * W4;
      const int col = (c4 < L4) ? (c4 << 2) : (R + ((c4 - L4) << 2));
      *reinterpret_cast<float4*>(&Ob[(size_t)(i0 + r) * T_ + col]) = z4;
    }
  }

  for (int jt = 0; jt < 3; ++jt) {
    const int j0 = i0 - 256 + jt * 128;
    if (j0 + 128 <= 0) continue;   // sub-tile entirely at j<0: nothing to write

    __syncthreads();               // protect Bt from previous sub-tile's readers
    for (int e = tid; e < 64 * 128; e += 256) {
      const int d = e & 63, r = e >> 6;
      const int j = j0 + r;
      Bt[d * LDP + r] = (j >= 0) ? Pb[(size_t)j * D_ + d] : 0.f;
    }
    __syncthreads();

    float acc[8][8];
    #pragma unroll
    for (int ii = 0; ii < 8; ++ii)
      #pragma unroll
      for (int jj = 0; jj < 8; ++jj) acc[ii][jj] = 0.f;

    const float* Ap = &At[ty * 8];
    const float* Bp = &Bt[tx * 8];
    for (int d = 0; d < 64; ++d) {
      const float4 a0 = *reinterpret_cast<const float4*>(&Ap[d * LDP]);
      const float4 a1 = *reinterpret_cast<const float4*>(&Ap[d * LDP + 4]);
      const float4 b0 = *reinterpret_cast<const float4*>(&Bp[d * LDP]);
      const float4 b1 = *reinterpret_cast<const float4*>(&Bp[d * LDP + 4]);
      const float a[8] = {a0.x, a0.y, a0.z, a0.w, a1.x, a1.y, a1.z, a1.w};
      const float b[8] = {b0.x, b0.y, b0.z, b0.w, b1.x, b1.y, b1.z, b1.w};
      #pragma unroll
      for (int ii = 0; ii < 8; ++ii)
        #pragma unroll
        for (int jj = 0; jj < 8; ++jj)
          acc[ii][jj] = fmaf(a[ii], b[jj], acc[ii][jj]);
    }

    // masked write of this 128x128 sub-tile (normalization already folded into gfs)
    #pragma unroll
    for (int ii = 0; ii < 8; ++ii) {
      const int i = i0 + ty * 8 + ii;
      float* orow = &Ob[(size_t)i * T_];
      #pragma unroll
      for (int jq = 0; jq < 2; ++jq) {
        const int jb = j0 + tx * 8 + jq * 4;
        if (jb < 0) continue;      // aligned: whole float4 is either >=0 or <0
        float4 v;
        float* vp = reinterpret_cast<float*>(&v);
        #pragma unroll
        for (int q = 0; q < 4; ++q) {
          const int j = jb + q;
          vp[q] = ((unsigned)(i - j) < 256u) ? acc[ii][jq * 4 + q] : 0.f;
        }
        *reinterpret_cast<float4*>(&orow[jb]) = v;
      }
    }
  }
}

extern "C" void kernel_launch(void* const* d_in, const int* in_sizes, int n_in,
                              void* d_out, int out_size, void* d_ws, size_t ws_size,
                              hipStream_t stream) {
  const float* pop = (const float*)d_in[0];
  float* out = (float*)d_out;
  float* gfs = (float*)d_ws;   // 32*2048*64 fp32 = 16.8 MB scratch

  dim3 blk(256);
  dim3 grd(T_ / 128, BH_);
  hipLaunchKernelGGL(k1_genefit, grd, blk, 0, stream, pop, gfs);
  hipLaunchKernelGGL(k2_orgfit, grd, blk, 0, stream, pop, gfs, out);
}

// Round 2
// 263.658 us; speedup vs baseline: 1.0243x; 1.0243x over previous
//
#include <hip/hip_runtime.h>
#include <cstdint>

#define T_  2048
#define D_  64
#define BH_ 32
#define W_  256
// LDS row stride: 132 floats = 528 B, 16B-aligned so float4 LDS reads are legal.
#define LDP 132

// Kernel 1: per (b,h,i): sliding-window sum over pop rows -> denom per d,
// wave-allreduce of 1/denom across the 64 lanes (lane == d), then store
// gfs[i][d] = gf[i][d] / rowsum_i  with rowsum_i = cnt*(64/suminv - 0.5) (analytic).
__global__ __launch_bounds__(256) void k1_genefit(const float* __restrict__ pop,
                                                  float* __restrict__ gfs) {
  const int bh = blockIdx.y;
  const int i0 = blockIdx.x * 128;
  const int w  = threadIdx.x >> 6;   // wave id: 4 waves, 32 rows each
  const int d  = threadIdx.x & 63;   // lane == feature dim
  const int ib = i0 + w * 32;

  const float* P = pop + (size_t)bh * T_ * D_ + d;
  float*       G = gfs + (size_t)bh * T_ * D_ + d;

  float isum = 0.f;
  int s0 = ib - (W_ - 1); if (s0 < 0) s0 = 0;
  for (int j = s0; j <= ib; ++j) isum += P[(size_t)j * D_];

  for (int r = 0; r < 32; ++r) {
    const int i = ib + r;
    if (r > 0) {
      isum += P[(size_t)i * D_];
      const int jd = i - W_;
      if (jd >= 0) isum -= P[(size_t)jd * D_];
    }
    const float cnt   = (i + 1 < W_) ? (float)(i + 1) : (float)W_;
    const float denom = isum / cnt + 0.5f;
    const float rinv  = 1.0f / denom;
    float s = rinv;
    #pragma unroll
    for (int m = 32; m >= 1; m >>= 1) s += __shfl_xor(s, m);
    float rowsum = cnt * (64.0f / s - 0.5f);
    rowsum = fmaxf(rowsum, 1e-10f);
    const float s2 = 1.0f / (rowsum * s);
    G[(size_t)i * D_] = rinv * s2;
  }
}

// Kernel 2: role-split. z=0: banded GEMM (3 diagonal 128x128 sub-tiles,
// masked writes). z=1: pure streaming zero-fill of the out-of-band row
// segments. Regions are disjoint -> no inter-block ordering needed; zero
// blocks carry no LDS so they co-schedule on top of LDS-limited band blocks.
__global__ __launch_bounds__(256) void k2_orgfit(const float* __restrict__ pop,
                                                 const float* __restrict__ gfs,
                                                 float* __restrict__ out) {
  const int bh  = blockIdx.y;
  const int i0  = blockIdx.x * 128;
  const int tid = threadIdx.x;
  float* Ob = out + (size_t)bh * T_ * T_;

  if (blockIdx.z == 1) {
    // -------- zero-fill role: division-free streaming --------
    const int w    = tid >> 6;
    const int lane = tid & 63;
    int L = i0 - 256; if (L < 0) L = 0;
    const int L4  = L >> 2;                // # left-segment float4s
    const int R   = i0 + 128;
    const int W4r = (T_ - R) >> 2;         // # right-segment float4s
    const float4 z4 = make_float4(0.f, 0.f, 0.f, 0.f);
    for (int r = w; r < 128; r += 4) {
      float* orow = Ob + (size_t)(i0 + r) * T_;
      float4* o4L = reinterpret_cast<float4*>(orow);
      for (int c = lane; c < L4; c += 64) o4L[c] = z4;
      float4* o4R = reinterpret_cast<float4*>(orow + R);
      for (int c = lane; c < W4r; c += 64) o4R[c] = z4;
    }
    return;
  }

  // -------- band role --------
  __shared__ float At[64 * LDP];
  __shared__ float Bt[64 * LDP];
  const int tx = tid & 15;
  const int ty = tid >> 4;

  const float* Pb = pop + (size_t)bh * T_ * D_;
  const float* Gb = gfs + (size_t)bh * T_ * D_;

  // stage A (gfs rows i0..i0+127), transposed, float4 global loads
  for (int e = tid; e < 64 * 128 / 4; e += 256) {
    const int d4 = e & 15, r = e >> 4;
    const float4 v = *reinterpret_cast<const float4*>(&Gb[(size_t)(i0 + r) * D_ + d4 * 4]);
    At[(d4 * 4 + 0) * LDP + r] = v.x;
    At[(d4 * 4 + 1) * LDP + r] = v.y;
    At[(d4 * 4 + 2) * LDP + r] = v.z;
    At[(d4 * 4 + 3) * LDP + r] = v.w;
  }

  for (int jt = 0; jt < 3; ++jt) {
    const int j0 = i0 - 256 + jt * 128;
    if (j0 + 128 <= 0) continue;           // sub-tile entirely at j<0

    __syncthreads();                       // protect Bt from prior readers
    for (int e = tid; e < 64 * 128 / 4; e += 256) {
      const int d4 = e & 15, r = e >> 4;
      const int j = j0 + r;
      float4 v = make_float4(0.f, 0.f, 0.f, 0.f);
      if (j >= 0) v = *reinterpret_cast<const float4*>(&Pb[(size_t)j * D_ + d4 * 4]);
      Bt[(d4 * 4 + 0) * LDP + r] = v.x;
      Bt[(d4 * 4 + 1) * LDP + r] = v.y;
      Bt[(d4 * 4 + 2) * LDP + r] = v.z;
      Bt[(d4 * 4 + 3) * LDP + r] = v.w;
    }
    __syncthreads();

    float acc[8][8];
    #pragma unroll
    for (int ii = 0; ii < 8; ++ii)
      #pragma unroll
      for (int jj = 0; jj < 8; ++jj) acc[ii][jj] = 0.f;

    const float* Ap = &At[ty * 8];
    const float* Bp = &Bt[tx * 8];
    for (int d = 0; d < 64; ++d) {
      const float4 a0 = *reinterpret_cast<const float4*>(&Ap[d * LDP]);
      const float4 a1 = *reinterpret_cast<const float4*>(&Ap[d * LDP + 4]);
      const float4 b0 = *reinterpret_cast<const float4*>(&Bp[d * LDP]);
      const float4 b1 = *reinterpret_cast<const float4*>(&Bp[d * LDP + 4]);
      const float a[8] = {a0.x, a0.y, a0.z, a0.w, a1.x, a1.y, a1.z, a1.w};
      const float b[8] = {b0.x, b0.y, b0.z, b0.w, b1.x, b1.y, b1.z, b1.w};
      #pragma unroll
      for (int ii = 0; ii < 8; ++ii)
        #pragma unroll
        for (int jj = 0; jj < 8; ++jj)
          acc[ii][jj] = fmaf(a[ii], b[jj], acc[ii][jj]);
    }

    // masked write of this 128x128 sub-tile (normalization folded into gfs)
    #pragma unroll
    for (int ii = 0; ii < 8; ++ii) {
      const int i = i0 + ty * 8 + ii;
      float* orow = &Ob[(size_t)i * T_];
      #pragma unroll
      for (int jq = 0; jq < 2; ++jq) {
        const int jb = j0 + tx * 8 + jq * 4;
        if (jb < 0) continue;              // aligned: whole float4 either side
        float4 v;
        float* vp = reinterpret_cast<float*>(&v);
        #pragma unroll
        for (int q = 0; q < 4; ++q) {
          const int j = jb + q;
          vp[q] = ((unsigned)(i - j) < 256u) ? acc[ii][jq * 4 + q] : 0.f;
        }
        *reinterpret_cast<float4*>(&orow[jb]) = v;
      }
    }
  }
}

extern "C" void kernel_launch(void* const* d_in, const int* in_sizes, int n_in,
                              void* d_out, int out_size, void* d_ws, size_t ws_size,
                              hipStream_t stream) {
  const float* pop = (const float*)d_in[0];
  float* out = (float*)d_out;
  float* gfs = (float*)d_ws;   // 32*2048*64 fp32 = 16.8 MB scratch

  dim3 blk(256);
  dim3 g1(T_ / 128, BH_);
  hipLaunchKernelGGL(k1_genefit, g1, blk, 0, stream, pop, gfs);
  dim3 g2(T_ / 128, BH_, 2);   // z=0 band blocks, z=1 zero-fill blocks
  hipLaunchKernelGGL(k2_orgfit, g2, blk, 0, stream, pop, gfs, out);
}

// Round 3
// 230.643 us; speedup vs baseline: 1.1709x; 1.1431x over previous
//
#include <hip/hip_runtime.h>
#include <cstdint>

#define T_  2048
#define D_  64
#define BH_ 32
#define W_  256
// LDS row stride: 132 floats = 528 B (16B-aligned rows so float4 LDS reads are legal).
#define LDP 132

// One fused kernel. Even blocks: band role (gene-fitness into LDS + banded GEMM
// with masked stores). Odd blocks: zero-fill role (stream zeros to the
// out-of-band row segments). Roles write disjoint regions -> no ordering needed;
// interleaved blockIdx means both roles are resident from t=0 (zero blocks have
// no LDS and co-schedule on top of the 2-blocks/CU LDS-bound band blocks).
__global__ __launch_bounds__(256) void fused_genfit(const float* __restrict__ pop,
                                                    float* __restrict__ out) {
  const int bid  = blockIdx.x;
  const int pair = bid >> 1;
  const int i0   = (pair & 15) * 128;
  const int bh   = pair >> 4;
  const int tid  = threadIdx.x;
  float* Ob = out + (size_t)bh * T_ * T_;

  if (bid & 1) {
    // -------- zero-fill role: division-free float4 streaming --------
    const int w = tid >> 6, lane = tid & 63;
    int L = i0 - 256; if (L < 0) L = 0;
    const int L4  = L >> 2;
    const int R   = i0 + 128;
    const int W4r = (T_ - R) >> 2;
    const float4 z4 = make_float4(0.f, 0.f, 0.f, 0.f);
    for (int r = w; r < 128; r += 4) {
      float* orow = Ob + (size_t)(i0 + r) * T_;
      float4* o4L = reinterpret_cast<float4*>(orow);
      for (int c = lane; c < L4; c += 64) o4L[c] = z4;
      float4* o4R = reinterpret_cast<float4*>(orow + R);
      for (int c = lane; c < W4r; c += 64) o4R[c] = z4;
    }
    return;
  }

  // -------- band role --------
  __shared__ float At[64 * LDP];
  __shared__ float Bt[64 * LDP];
  const float* Pb = pop + (size_t)bh * T_ * D_;

  // gene fitness for rows i0..i0+127, normalized analytically, directly into
  // the transposed LDS A-tile. rowsum_i = cnt*(64/suminv - 0.5) closed form.
  {
    const int w = tid >> 6;         // wave id: 4 waves x 32 rows
    const int d = tid & 63;         // lane == feature dim
    const int ib = i0 + w * 32;
    const float* P = Pb + d;
    int s0 = ib - (W_ - 1); if (s0 < 0) s0 = 0;
    const int jend = ib + 1;
    // 8-wide independent partial sums for load ILP in the window init
    float p0=0.f,p1=0.f,p2=0.f,p3=0.f,p4=0.f,p5=0.f,p6=0.f,p7=0.f;
    int j = s0;
    for (; j + 8 <= jend; j += 8) {
      p0 += P[(size_t)(j+0)*D_]; p1 += P[(size_t)(j+1)*D_];
      p2 += P[(size_t)(j+2)*D_]; p3 += P[(size_t)(j+3)*D_];
      p4 += P[(size_t)(j+4)*D_]; p5 += P[(size_t)(j+5)*D_];
      p6 += P[(size_t)(j+6)*D_]; p7 += P[(size_t)(j+7)*D_];
    }
    for (; j < jend; ++j) p0 += P[(size_t)j*D_];
    float isum = ((p0+p1)+(p2+p3)) + ((p4+p5)+(p6+p7));

    for (int r = 0; r < 32; ++r) {
      const int i = ib + r;
      if (r > 0) {
        isum += P[(size_t)i * D_];
        const int jd = i - W_;
        if (jd >= 0) isum -= P[(size_t)jd * D_];
      }
      const float cnt   = (i + 1 < W_) ? (float)(i + 1) : (float)W_;
      const float denom = isum / cnt + 0.5f;
      const float rinv  = 1.0f / denom;
      float s = rinv;
      #pragma unroll
      for (int m = 32; m >= 1; m >>= 1) s += __shfl_xor(s, m);
      float rowsum = cnt * (64.0f / s - 0.5f);
      rowsum = fmaxf(rowsum, 1e-10f);
      At[d * LDP + w * 32 + r] = rinv / (rowsum * s);
    }
  }
  // At-writes are ordered before any At-read by the barriers inside the jt loop.

  for (int jt = 0; jt < 3; ++jt) {
    const int j0 = i0 - 256 + jt * 128;
    if (j0 + 128 <= 0) continue;           // sub-tile entirely at j<0

    __syncthreads();                       // protect Bt from prior readers / order At
    for (int e = tid; e < 64 * 128 / 4; e += 256) {
      const int d4 = e & 15, r = e >> 4;
      const int jj = j0 + r;
      float4 v = make_float4(0.f, 0.f, 0.f, 0.f);
      if (jj >= 0) v = *reinterpret_cast<const float4*>(&Pb[(size_t)jj * D_ + d4 * 4]);
      Bt[(d4 * 4 + 0) * LDP + r] = v.x;
      Bt[(d4 * 4 + 1) * LDP + r] = v.y;
      Bt[(d4 * 4 + 2) * LDP + r] = v.z;
      Bt[(d4 * 4 + 3) * LDP + r] = v.w;
    }
    __syncthreads();

    const int tx = tid & 15;
    const int ty = tid >> 4;
    float acc[8][8];
    #pragma unroll
    for (int ii = 0; ii < 8; ++ii)
      #pragma unroll
      for (int jj = 0; jj < 8; ++jj) acc[ii][jj] = 0.f;

    const float* Ap = &At[ty * 8];
    const float* Bp = &Bt[tx * 8];
    for (int dd = 0; dd < 64; ++dd) {
      const float4 a0 = *reinterpret_cast<const float4*>(&Ap[dd * LDP]);
      const float4 a1 = *reinterpret_cast<const float4*>(&Ap[dd * LDP + 4]);
      const float4 b0 = *reinterpret_cast<const float4*>(&Bp[dd * LDP]);
      const float4 b1 = *reinterpret_cast<const float4*>(&Bp[dd * LDP + 4]);
      const float a[8] = {a0.x, a0.y, a0.z, a0.w, a1.x, a1.y, a1.z, a1.w};
      const float b[8] = {b0.x, b0.y, b0.z, b0.w, b1.x, b1.y, b1.z, b1.w};
      #pragma unroll
      for (int ii = 0; ii < 8; ++ii)
        #pragma unroll
        for (int jj = 0; jj < 8; ++jj)
          acc[ii][jj] = fmaf(a[ii], b[jj], acc[ii][jj]);
    }

    // masked write (normalization already folded into the A-tile values)
    #pragma unroll
    for (int ii = 0; ii < 8; ++ii) {
      const int i = i0 + ty * 8 + ii;
      float* orow = &Ob[(size_t)i * T_];
      #pragma unroll
      for (int jq = 0; jq < 2; ++jq) {
        const int jb = j0 + tx * 8 + jq * 4;
        if (jb < 0) continue;              // aligned: whole float4 on one side
        float4 v;
        float* vp = reinterpret_cast<float*>(&v);
        #pragma unroll
        for (int q = 0; q < 4; ++q) {
          const int jcol = jb + q;
          vp[q] = ((unsigned)(i - jcol) < 256u) ? acc[ii][jq * 4 + q] : 0.f;
        }
        *reinterpret_cast<float4*>(&orow[jb]) = v;
      }
    }
  }
}

extern "C" void kernel_launch(void* const* d_in, const int* in_sizes, int n_in,
                              void* d_out, int out_size, void* d_ws, size_t ws_size,
                              hipStream_t stream) {
  const float* pop = (const float*)d_in[0];
  float* out = (float*)d_out;
  dim3 blk(256);
  dim3 grd(2 * 16 * BH_);   // 512 band + 512 zero blocks, interleaved by parity
  hipLaunchKernelGGL(fused_genfit, grd, blk, 0, stream, pop, out);
}

// Round 5
// 176.674 us; speedup vs baseline: 1.5286x; 1.3055x over previous
//
#include <hip/hip_runtime.h>
#include <cstdint>

#define T_  2048
#define D_  64
#define BH_ 32
#define W_  256
// LDS row stride: 132 floats = 528 B (16B-aligned rows so float4 LDS reads are legal).
#define LDP 132

typedef float f32x4 __attribute__((ext_vector_type(4)));

// Band kernel: per (bh, 128-row i-tile): gene-fitness (normalization folded in,
// closed-form rowsum) into transposed LDS A-tile, then 3 diagonal 128x128
// banded-GEMM sub-tiles with masked stores.
// Thread (tx,ty) owns rows ty*8..+7, cols {tx*4..+3, 64+tx*4..+3}:
//  - LDS B-read addresses tx*4 mod 32 -> 2-way bank aliasing (free on CDNA4)
//  - stores are 256B-contiguous per 16-lane group.
__global__ __launch_bounds__(256) void k_band(const float* __restrict__ pop,
                                              float* __restrict__ out) {
  __shared__ float At[64 * LDP];
  __shared__ float Bt[64 * LDP];
  const int pair = blockIdx.x;
  const int i0   = (pair & 15) * 128;
  const int bh   = pair >> 4;
  const int tid  = threadIdx.x;
  const float* Pb = pop + (size_t)bh * T_ * D_;
  float*       Ob = out + (size_t)bh * T_ * T_;

  // ---- gene fitness rows i0..i0+127 -> At (transposed) ----
  {
    const int w = tid >> 6;        // 4 waves x 32 rows
    const int d = tid & 63;        // lane == feature dim
    const int ib = i0 + w * 32;
    const float* P = Pb + d;
    int s0 = ib - (W_ - 1); if (s0 < 0) s0 = 0;
    const int jend = ib + 1;
    float p0=0.f,p1=0.f,p2=0.f,p3=0.f,p4=0.f,p5=0.f,p6=0.f,p7=0.f;
    int j = s0;
    for (; j + 8 <= jend; j += 8) {
      p0 += P[(size_t)(j+0)*D_]; p1 += P[(size_t)(j+1)*D_];
      p2 += P[(size_t)(j+2)*D_]; p3 += P[(size_t)(j+3)*D_];
      p4 += P[(size_t)(j+4)*D_]; p5 += P[(size_t)(j+5)*D_];
      p6 += P[(size_t)(j+6)*D_]; p7 += P[(size_t)(j+7)*D_];
    }
    for (; j < jend; ++j) p0 += P[(size_t)j*D_];
    float isum = ((p0+p1)+(p2+p3)) + ((p4+p5)+(p6+p7));

    for (int r = 0; r < 32; ++r) {
      const int i = ib + r;
      if (r > 0) {
        isum += P[(size_t)i * D_];
        const int jd = i - W_;
        if (jd >= 0) isum -= P[(size_t)jd * D_];
      }
      const float cnt   = (i + 1 < W_) ? (float)(i + 1) : (float)W_;
      const float denom = isum / cnt + 0.5f;
      const float rinv  = 1.0f / denom;
      float s = rinv;
      #pragma unroll
      for (int m = 32; m >= 1; m >>= 1) s += __shfl_xor(s, m);
      float rowsum = cnt * (64.0f / s - 0.5f);
      rowsum = fmaxf(rowsum, 1e-10f);
      At[d * LDP + w * 32 + r] = rinv / (rowsum * s);
    }
  }

  for (int jt = 0; jt < 3; ++jt) {
    const int j0 = i0 - 256 + jt * 128;
    if (j0 + 128 <= 0) continue;

    __syncthreads();                       // order At writes / protect Bt
    for (int e = tid; e < 64 * 128 / 4; e += 256) {
      const int d4 = e & 15, r = e >> 4;
      const int jj = j0 + r;
      float4 v = make_float4(0.f, 0.f, 0.f, 0.f);
      if (jj >= 0) v = *reinterpret_cast<const float4*>(&Pb[(size_t)jj * D_ + d4 * 4]);
      Bt[(d4 * 4 + 0) * LDP + r] = v.x;
      Bt[(d4 * 4 + 1) * LDP + r] = v.y;
      Bt[(d4 * 4 + 2) * LDP + r] = v.z;
      Bt[(d4 * 4 + 3) * LDP + r] = v.w;
    }
    __syncthreads();

    const int tx = tid & 15;
    const int ty = tid >> 4;
    float acc[8][8];
    #pragma unroll
    for (int ii = 0; ii < 8; ++ii)
      #pragma unroll
      for (int jj = 0; jj < 8; ++jj) acc[ii][jj] = 0.f;

    const float* Ap = &At[ty * 8];
    const float* Bp = &Bt[tx * 4];
    for (int dd = 0; dd < 64; ++dd) {
      const float4 a0 = *reinterpret_cast<const float4*>(&Ap[dd * LDP]);
      const float4 a1 = *reinterpret_cast<const float4*>(&Ap[dd * LDP + 4]);
      const float4 b0 = *reinterpret_cast<const float4*>(&Bp[dd * LDP]);        // cols tx*4..+3
      const float4 b1 = *reinterpret_cast<const float4*>(&Bp[dd * LDP + 64]);   // cols 64+tx*4..+3
      const float a[8] = {a0.x, a0.y, a0.z, a0.w, a1.x, a1.y, a1.z, a1.w};
      const float b[8] = {b0.x, b0.y, b0.z, b0.w, b1.x, b1.y, b1.z, b1.w};
      #pragma unroll
      for (int ii = 0; ii < 8; ++ii)
        #pragma unroll
        for (int jj = 0; jj < 8; ++jj)
          acc[ii][jj] = fmaf(a[ii], b[jj], acc[ii][jj]);
    }

    #pragma unroll
    for (int ii = 0; ii < 8; ++ii) {
      const int i = i0 + ty * 8 + ii;
      float* orow = &Ob[(size_t)i * T_];
      #pragma unroll
      for (int jh = 0; jh < 2; ++jh) {
        const int jb = j0 + jh * 64 + tx * 4;
        if (jb < 0) continue;              // jb % 4 == 0: whole float4 one side
        float4 v;
        float* vp = reinterpret_cast<float*>(&v);
        #pragma unroll
        for (int q = 0; q < 4; ++q) {
          const int jcol = jb + q;
          vp[q] = ((unsigned)(i - jcol) < 256u) ? acc[ii][jh * 4 + q] : 0.f;
        }
        *reinterpret_cast<float4*>(&orow[jb]) = v;
      }
    }
  }
}

// Zero kernel: streams zeros (non-temporal) to the out-of-band segments.
__global__ __launch_bounds__(256) void k_zero(float* __restrict__ out) {
  const int pair = blockIdx.x;
  const int i0   = (pair & 15) * 128;
  const int bh   = pair >> 4;
  const int tid  = threadIdx.x;
  float* Ob = out + (size_t)bh * T_ * T_;

  const int w = tid >> 6, lane = tid & 63;
  int L = i0 - 256; if (L < 0) L = 0;
  const int L4  = L >> 2;
  const int R   = i0 + 128;
  const int W4r = (T_ - R) >> 2;
  const f32x4 z4 = {0.f, 0.f, 0.f, 0.f};
  for (int r = w; r < 128; r += 4) {
    float* orow = Ob + (size_t)(i0 + r) * T_;
    f32x4* o4L = reinterpret_cast<f32x4*>(orow);
    for (int c = lane; c < L4; c += 64)
      __builtin_nontemporal_store(z4, &o4L[c]);
    f32x4* o4R = reinterpret_cast<f32x4*>(orow + R);
    for (int c = lane; c < W4r; c += 64)
      __builtin_nontemporal_store(z4, &o4R[c]);
  }
}

extern "C" void kernel_launch(void* const* d_in, const int* in_sizes, int n_in,
                              void* d_out, int out_size, void* d_ws, size_t ws_size,
                              hipStream_t stream) {
  const float* pop = (const float*)d_in[0];
  float* out = (float*)d_out;
  dim3 blk(256);
  dim3 grd(16 * BH_);
  hipLaunchKernelGGL(k_band, grd, blk, 0, stream, pop, out);
  hipLaunchKernelGGL(k_zero, grd, blk, 0, stream, out);
}

// Round 6
// 174.867 us; speedup vs baseline: 1.5444x; 1.0103x over previous
//
#include <hip/hip_runtime.h>
#include <cstdint>

#define T_  2048
#define D_  64
#define BH_ 32
#define W_  256
// LDS row stride: 132 floats = 528 B (16B-aligned rows so float4 LDS reads are legal).
#define LDP 132

typedef float f32x4 __attribute__((ext_vector_type(4)));

// One kernel, 1024 blocks. Role interleave is XCD-safe: blocks [g*16, g*16+8)
// are band, [g*16+8, g*16+16) are zero-fill -> with round-robin bid%8 XCD
// assignment, every XCD gets an equal mix of both roles. Zero blocks carry no
// LDS so they co-schedule on top of the 2-blocks/CU LDS-bound band blocks and
// their writes overlap band compute. Regions are disjoint (no ordering needed).
__global__ __launch_bounds__(256) void fused_genfit(const float* __restrict__ pop,
                                                    float* __restrict__ out) {
  const int bid  = blockIdx.x;
  const int grp  = bid >> 4;
  const int sub  = bid & 15;
  const int unit = grp * 8 + (sub & 7);     // 0..511
  const int i0   = (unit & 15) * 128;
  const int bh   = unit >> 4;
  const int tid  = threadIdx.x;
  float* Ob = out + (size_t)bh * T_ * T_;

  if (sub >> 3) {
    // -------- zero-fill role: division-free non-temporal float4 streaming ----
    const int w = tid >> 6, lane = tid & 63;
    int L = i0 - 256; if (L < 0) L = 0;
    const int L4  = L >> 2;
    const int R   = i0 + 128;
    const int W4r = (T_ - R) >> 2;
    const f32x4 z4 = {0.f, 0.f, 0.f, 0.f};
    for (int r = w; r < 128; r += 4) {
      float* orow = Ob + (size_t)(i0 + r) * T_;
      f32x4* o4L = reinterpret_cast<f32x4*>(orow);
      for (int c = lane; c < L4; c += 64)
        __builtin_nontemporal_store(z4, &o4L[c]);
      f32x4* o4R = reinterpret_cast<f32x4*>(orow + R);
      for (int c = lane; c < W4r; c += 64)
        __builtin_nontemporal_store(z4, &o4R[c]);
    }
    return;
  }

  // -------- band role --------
  // Single LDS pool so the register-double-buffered inner loop may prefetch one
  // row past each tile without going out of bounds (garbage values unused).
  __shared__ float S[2 * 64 * LDP + 128];
  float* At = S;
  float* Bt = S + 64 * LDP;
  const float* Pb = pop + (size_t)bh * T_ * D_;

  // ---- gene fitness rows i0..i0+127 -> At (transposed), rowsum folded in ----
  {
    const int w = tid >> 6;        // 4 waves x 32 rows
    const int d = tid & 63;        // lane == feature dim
    const int ib = i0 + w * 32;
    const float* P = Pb + d;
    int s0 = ib - (W_ - 1); if (s0 < 0) s0 = 0;
    const int jend = ib + 1;
    float p0=0.f,p1=0.f,p2=0.f,p3=0.f,p4=0.f,p5=0.f,p6=0.f,p7=0.f;
    int j = s0;
    for (; j + 8 <= jend; j += 8) {
      p0 += P[(size_t)(j+0)*D_]; p1 += P[(size_t)(j+1)*D_];
      p2 += P[(size_t)(j+2)*D_]; p3 += P[(size_t)(j+3)*D_];
      p4 += P[(size_t)(j+4)*D_]; p5 += P[(size_t)(j+5)*D_];
      p6 += P[(size_t)(j+6)*D_]; p7 += P[(size_t)(j+7)*D_];
    }
    for (; j < jend; ++j) p0 += P[(size_t)j*D_];
    float isum = ((p0+p1)+(p2+p3)) + ((p4+p5)+(p6+p7));

    for (int r = 0; r < 32; ++r) {
      const int i = ib + r;
      if (r > 0) {
        isum += P[(size_t)i * D_];
        const int jd = i - W_;
        if (jd >= 0) isum -= P[(size_t)jd * D_];
      }
      const float cnt   = (i + 1 < W_) ? (float)(i + 1) : (float)W_;
      const float denom = isum / cnt + 0.5f;
      const float rinv  = 1.0f / denom;
      float s = rinv;
      #pragma unroll
      for (int m = 32; m >= 1; m >>= 1) s += __shfl_xor(s, m);
      float rowsum = cnt * (64.0f / s - 0.5f);
      rowsum = fmaxf(rowsum, 1e-10f);
      At[d * LDP + w * 32 + r] = rinv / (rowsum * s);
    }
  }

  for (int jt = 0; jt < 3; ++jt) {
    const int j0 = i0 - 256 + jt * 128;
    if (j0 + 128 <= 0) continue;           // uniform across block: barrier-safe

    __syncthreads();                       // order At writes / protect Bt
    for (int e = tid; e < 64 * 128 / 4; e += 256) {
      const int d4 = e & 15, r = e >> 4;
      const int jj = j0 + r;
      f32x4 v = {0.f, 0.f, 0.f, 0.f};
      if (jj >= 0) v = *reinterpret_cast<const f32x4*>(&Pb[(size_t)jj * D_ + d4 * 4]);
      Bt[(d4 * 4 + 0) * LDP + r] = v.x;
      Bt[(d4 * 4 + 1) * LDP + r] = v.y;
      Bt[(d4 * 4 + 2) * LDP + r] = v.z;
      Bt[(d4 * 4 + 3) * LDP + r] = v.w;
    }
    __syncthreads();

    const int tx = tid & 15;
    const int ty = tid >> 4;
    float acc[8][8];
    #pragma unroll
    for (int ii = 0; ii < 8; ++ii)
      #pragma unroll
      for (int jj = 0; jj < 8; ++jj) acc[ii][jj] = 0.f;

    const float* Ap = &At[ty * 8];
    const float* Bp = &Bt[tx * 4];
    // register double-buffer: prefetch dd+1 fragments before the 64-FMA block
    f32x4 a0 = *reinterpret_cast<const f32x4*>(&Ap[0]);
    f32x4 a1 = *reinterpret_cast<const f32x4*>(&Ap[4]);
    f32x4 b0 = *reinterpret_cast<const f32x4*>(&Bp[0]);
    f32x4 b1 = *reinterpret_cast<const f32x4*>(&Bp[64]);
    for (int dd = 0; dd < 64; ++dd) {
      const float* Apn = Ap + (dd + 1) * LDP;   // dd=63 reads pad: unused
      const float* Bpn = Bp + (dd + 1) * LDP;
      const f32x4 na0 = *reinterpret_cast<const f32x4*>(&Apn[0]);
      const f32x4 na1 = *reinterpret_cast<const f32x4*>(&Apn[4]);
      const f32x4 nb0 = *reinterpret_cast<const f32x4*>(&Bpn[0]);
      const f32x4 nb1 = *reinterpret_cast<const f32x4*>(&Bpn[64]);
      const float a[8] = {a0.x, a0.y, a0.z, a0.w, a1.x, a1.y, a1.z, a1.w};
      const float b[8] = {b0.x, b0.y, b0.z, b0.w, b1.x, b1.y, b1.z, b1.w};
      #pragma unroll
      for (int ii = 0; ii < 8; ++ii)
        #pragma unroll
        for (int jj = 0; jj < 8; ++jj)
          acc[ii][jj] = fmaf(a[ii], b[jj], acc[ii][jj]);
      a0 = na0; a1 = na1; b0 = nb0; b1 = nb1;
    }

    // masked non-temporal stores (normalization folded into At values)
    #pragma unroll
    for (int ii = 0; ii < 8; ++ii) {
      const int i = i0 + ty * 8 + ii;
      float* orow = &Ob[(size_t)i * T_];
      #pragma unroll
      for (int jh = 0; jh < 2; ++jh) {
        const int jb = j0 + jh * 64 + tx * 4;
        if (jb < 0) continue;
        f32x4 v;
        #pragma unroll
        for (int q = 0; q < 4; ++q) {
          const int jcol = jb + q;
          v[q] = ((unsigned)(i - jcol) < 256u) ? acc[ii][jh * 4 + q] : 0.f;
        }
        __builtin_nontemporal_store(v, reinterpret_cast<f32x4*>(&orow[jb]));
      }
    }
  }
}

extern "C" void kernel_launch(void* const* d_in, const int* in_sizes, int n_in,
                              void* d_out, int out_size, void* d_ws, size_t ws_size,
                              hipStream_t stream) {
  const float* pop = (const float*)d_in[0];
  float* out = (float*)d_out;
  dim3 blk(256);
  dim3 grd(2 * 16 * BH_);   // 512 band + 512 zero, XCD-safe interleave by groups of 8
  hipLaunchKernelGGL(fused_genfit, grd, blk, 0, stream, pop, out);
}